// Round 12
// baseline (388.107 us; speedup 1.0000x reference)
//
#include <hip/hip_runtime.h>
#include <math.h>

#define BB 16
#define SS 512
#define DD 256
#define HH 8
#define HDIM 32
#define FFD 1024
#define NL 2
#define NSOUT 1024
#define SD (SS*DD)      // 131072
#define ROWS (BB*SS)    // 8192

#define HEAD_KC 256
#define HEAD_NCH 512    // SD / HEAD_KC

typedef __attribute__((ext_vector_type(8))) short short8;
typedef __attribute__((ext_vector_type(4))) float f32x4;

__device__ __forceinline__ unsigned short f2bf(float f) {
    union { float f; unsigned u; } c; c.f = f;
    unsigned u = c.u + 0x7fffu + ((c.u >> 16) & 1u);
    return (unsigned short)(u >> 16);
}

// ------- one-shot prep: weight transposes + rope tables + input projection -------
__global__ __launch_bounds__(256) void k_prep_all(
    const float* __restrict__ p_qw, const float* __restrict__ p_kw,
    const float* __restrict__ p_vw, const float* __restrict__ p_ow,
    const float* __restrict__ p_f1w, const float* __restrict__ p_f2w,
    unsigned short* __restrict__ wq, unsigned short* __restrict__ wk,
    unsigned short* __restrict__ wv, unsigned short* __restrict__ wo,
    unsigned short* __restrict__ wf1, unsigned short* __restrict__ wf2,
    float* __restrict__ ct, float* __restrict__ st,
    const float* __restrict__ values, const float* __restrict__ dib,
    const float* __restrict__ gamma, const float* __restrict__ mtyp,
    const float* __restrict__ in_w, const float* __restrict__ in_b,
    float* __restrict__ x) {
    int bid = blockIdx.x;
    int t = threadIdx.x;
    if (bid >= 1568) {   // input projection: 2048 blocks
        int i = (bid - 1568) * 256 + t;   // ROWS*64
        int row = i >> 6, d4 = (i & 63) * 4;
        float v = values[row];
        float f0 = (v >= 0.f) ? 1.f : -1.f;
        float f1 = fabsf(v);
        float f2 = gamma[row];
        float f3 = dib[row];
        float f4 = mtyp[row] * 2.f - 1.f;
        float4 w0 = *(const float4*)&in_w[d4];
        float4 w1 = *(const float4*)&in_w[DD + d4];
        float4 w2 = *(const float4*)&in_w[2 * DD + d4];
        float4 w3 = *(const float4*)&in_w[3 * DD + d4];
        float4 w4 = *(const float4*)&in_w[4 * DD + d4];
        float4 bb = *(const float4*)&in_b[d4];
        float4 o;
        o.x = f0 * w0.x + f1 * w1.x + f2 * w2.x + f3 * w3.x + f4 * w4.x + bb.x;
        o.y = f0 * w0.y + f1 * w1.y + f2 * w2.y + f3 * w3.y + f4 * w4.y + bb.y;
        o.z = f0 * w0.z + f1 * w1.z + f2 * w2.z + f3 * w3.z + f4 * w4.z + bb.z;
        o.w = f0 * w0.w + f1 * w1.w + f2 * w2.w + f3 * w3.w + f4 * w4.w + bb.w;
        *(float4*)&x[(size_t)row * DD + d4] = o;
        return;
    }
    if (bid >= 1536) {   // rope tables
        int i = (bid - 1536) * 256 + t;
        if (i < SS * 16) {
            int s = i >> 4, f = i & 15;
            float invf = powf(10000.f, -(float)f / 16.f);
            float ang = (float)s * invf;
            ct[i] = cosf(ang);
            st[i] = sinf(ang);
        }
        return;
    }
    const float* src; unsigned short* dst;
    int K, N, kx, nx, l;
    if (bid < 512) {
        int grp = bid >> 7, r = bid & 127; l = r >> 6; int tl = r & 63;
        kx = tl >> 3; nx = tl & 7; K = DD; N = DD;
        src = grp == 0 ? p_qw : grp == 1 ? p_kw : grp == 2 ? p_vw : p_ow;
        dst = grp == 0 ? wq : grp == 1 ? wk : grp == 2 ? wv : wo;
    } else if (bid < 1024) {
        int r = bid - 512; l = r >> 8; int tl = r & 255;
        kx = tl >> 5; nx = tl & 31; K = DD; N = FFD; src = p_f1w; dst = wf1;
    } else {
        int r = bid - 1024; l = r >> 8; int tl = r & 255;
        kx = tl >> 3; nx = tl & 7; K = FFD; N = DD; src = p_f2w; dst = wf2;
    }
    __shared__ float tile[32][33];
    size_t zo = (size_t)l * K * N;
    int k0 = kx * 32, n0 = nx * 32;
    int r_ = t >> 3, c4 = (t & 7) * 4;
    float4 a = *(const float4*)&src[zo + (size_t)(k0 + r_) * N + n0 + c4];
    tile[r_][c4 + 0] = a.x; tile[r_][c4 + 1] = a.y; tile[r_][c4 + 2] = a.z; tile[r_][c4 + 3] = a.w;
    __syncthreads();
    unsigned o0 = f2bf(tile[c4 + 0][r_]), o1 = f2bf(tile[c4 + 1][r_]);
    unsigned o2 = f2bf(tile[c4 + 2][r_]), o3 = f2bf(tile[c4 + 3][r_]);
    uint2 ud = { o0 | (o1 << 16), o2 | (o3 << 16) };
    *(uint2*)&dst[zo + (size_t)(n0 + r_) * K + k0 + c4] = ud;
}

// ---------------- wave-per-row layernorm over D=256, no barriers ----------------
template <bool OBF>
__global__ __launch_bounds__(256) void k_layernorm_w(
    const float* __restrict__ in, void* __restrict__ outp,
    const float* __restrict__ sc, const float* __restrict__ bi) {
    int t = threadIdx.x, lane = t & 63, w = t >> 6;
    int row = blockIdx.x * 4 + w;
    float4 v = *(const float4*)&in[(size_t)row * DD + lane * 4];
    float s1 = v.x + v.y + v.z + v.w;
    float s2 = v.x * v.x + v.y * v.y + v.z * v.z + v.w * v.w;
#pragma unroll
    for (int off = 32; off > 0; off >>= 1) {
        s1 += __shfl_xor(s1, off);
        s2 += __shfl_xor(s2, off);
    }
    float mean = s1 * (1.f / DD);
    float var = s2 * (1.f / DD) - mean * mean;
    float rstd = rsqrtf(var + 1e-5f);
    float4 sv = *(const float4*)&sc[lane * 4];
    float4 bv = *(const float4*)&bi[lane * 4];
    float o0 = (v.x - mean) * rstd * sv.x + bv.x;
    float o1 = (v.y - mean) * rstd * sv.y + bv.y;
    float o2 = (v.z - mean) * rstd * sv.z + bv.z;
    float o3 = (v.w - mean) * rstd * sv.w + bv.w;
    if (OBF) {
        ushort4 u = { f2bf(o0), f2bf(o1), f2bf(o2), f2bf(o3) };
        *(ushort4*)&((unsigned short*)outp)[(size_t)row * DD + lane * 4] = u;
    } else {
        float4 o = { o0, o1, o2, o3 };
        *(float4*)&((float*)outp)[(size_t)row * DD + lane * 4] = o;
    }
}

// ---------------- bf16 MFMA GEMM 128x128 (FF1): C = A@Bt^T + bias, exact GELU, bf16 out
__global__ __launch_bounds__(256) void k_gemm_ff1(
    const short* __restrict__ A, const short* __restrict__ Bt,
    const float* __restrict__ bias, unsigned short* __restrict__ Cout,
    int M, int N, int K) {
    __shared__ __align__(16) short As[128 * 32];
    __shared__ __align__(16) short Bs[128 * 32];
    int t = threadIdx.x;
    int lane = t & 63, wid = t >> 6;
    int wr = wid >> 1, wc = wid & 1;
    int m0 = blockIdx.x * 128, n0 = blockIdx.y * 128;
    f32x4 acc[4][4] = {};
    int srow = t >> 2, sslot = t & 3;
    for (int k0 = 0; k0 < K; k0 += 32) {
#pragma unroll
        for (int p = 0; p < 2; ++p) {
            int row = srow + p * 64;
            int sw = sslot ^ ((row >> 1) & 3);
            *(float4*)&As[row * 32 + sw * 8] =
                *(const float4*)&A[(size_t)(m0 + row) * K + k0 + sslot * 8];
            *(float4*)&Bs[row * 32 + sw * 8] =
                *(const float4*)&Bt[(size_t)(n0 + row) * K + k0 + sslot * 8];
        }
        __syncthreads();
        short8 af[4], bfr[4];
#pragma unroll
        for (int mt = 0; mt < 4; ++mt) {
            int row = wr * 64 + mt * 16 + (lane & 15);
            int sl = (lane >> 4) ^ ((row >> 1) & 3);
            af[mt] = *(const short8*)&As[row * 32 + sl * 8];
        }
#pragma unroll
        for (int nt = 0; nt < 4; ++nt) {
            int row = wc * 64 + nt * 16 + (lane & 15);
            int sl = (lane >> 4) ^ ((row >> 1) & 3);
            bfr[nt] = *(const short8*)&Bs[row * 32 + sl * 8];
        }
#pragma unroll
        for (int mt = 0; mt < 4; ++mt)
#pragma unroll
            for (int nt = 0; nt < 4; ++nt)
                acc[mt][nt] = __builtin_amdgcn_mfma_f32_16x16x32_bf16(af[mt], bfr[nt], acc[mt][nt], 0, 0, 0);
        __syncthreads();
    }
#pragma unroll
    for (int mt = 0; mt < 4; ++mt) {
#pragma unroll
        for (int i = 0; i < 4; ++i) {
            int gm = m0 + wr * 64 + mt * 16 + (lane >> 4) * 4 + i;
#pragma unroll
            for (int nt = 0; nt < 4; ++nt) {
                int gn = n0 + wc * 64 + nt * 16 + (lane & 15);
                float v = acc[mt][nt][i] + bias[gn];
                v = 0.5f * v * (1.f + erff(v * 0.70710678118654752f));
                Cout[(size_t)gm * N + gn] = f2bf(v);
            }
        }
    }
}

// ---------------- bf16 MFMA GEMM 64x128, K_STEP=64 (O-proj / FF2), fp32 residual out
// Register-prefetch pipeline: next K-step's loads issue before MFMA of current step
// (1 block/CU -> 1 wave/SIMD; no co-resident wave hides latency, so ILP must).
template <int EPI>
__global__ __launch_bounds__(256) void k_gemm64(
    const short* __restrict__ A, const short* __restrict__ Bt,
    const float* __restrict__ bias, float* __restrict__ Cout,
    int M, int N, int K, const float* __restrict__ resx, const int* __restrict__ mask) {
    __shared__ __align__(16) short As[64 * 64];    // 8 KB
    __shared__ __align__(16) short Bs[128 * 64];   // 16 KB
    int t = threadIdx.x;
    int lane = t & 63, wid = t >> 6;
    int wr = wid >> 1, wc = wid & 1;          // wave: 32 rows x 64 cols
    int m0 = blockIdx.x * 64, n0 = blockIdx.y * 128;
    int l15 = lane & 15, lh = lane >> 4;
    f32x4 acc[2][4] = {};
    float4 ra[2], rb[4];
#pragma unroll
    for (int p = 0; p < 2; ++p) {
        int idx = t + p * 256;
        int row = idx >> 3, sl = idx & 7;
        ra[p] = *(const float4*)&A[(size_t)(m0 + row) * K + sl * 8];
    }
#pragma unroll
    for (int p = 0; p < 4; ++p) {
        int idx = t + p * 256;
        int row = idx >> 3, sl = idx & 7;
        rb[p] = *(const float4*)&Bt[(size_t)(n0 + row) * K + sl * 8];
    }
    for (int k0 = 0; k0 < K; k0 += 64) {
#pragma unroll
        for (int p = 0; p < 2; ++p) {
            int idx = t + p * 256;
            int row = idx >> 3, sl = idx & 7;
            int sw = sl ^ (row & 7);
            *(float4*)&As[row * 64 + sw * 8] = ra[p];
        }
#pragma unroll
        for (int p = 0; p < 4; ++p) {
            int idx = t + p * 256;
            int row = idx >> 3, sl = idx & 7;
            int sw = sl ^ (row & 7);
            *(float4*)&Bs[row * 64 + sw * 8] = rb[p];
        }
        __syncthreads();
        int kn = k0 + 64;
        if (kn < K) {
#pragma unroll
            for (int p = 0; p < 2; ++p) {
                int idx = t + p * 256;
                int row = idx >> 3, sl = idx & 7;
                ra[p] = *(const float4*)&A[(size_t)(m0 + row) * K + kn + sl * 8];
            }
#pragma unroll
            for (int p = 0; p < 4; ++p) {
                int idx = t + p * 256;
                int row = idx >> 3, sl = idx & 7;
                rb[p] = *(const float4*)&Bt[(size_t)(n0 + row) * K + kn + sl * 8];
            }
        }
#pragma unroll
        for (int kk = 0; kk < 2; ++kk) {
            short8 af[2], bfr[4];
#pragma unroll
            for (int mt = 0; mt < 2; ++mt) {
                int row = wr * 32 + mt * 16 + l15;
                int sl = (kk * 4 + lh) ^ (row & 7);
                af[mt] = *(const short8*)&As[row * 64 + sl * 8];
            }
#pragma unroll
            for (int nt = 0; nt < 4; ++nt) {
                int row = wc * 64 + nt * 16 + l15;
                int sl = (kk * 4 + lh) ^ (row & 7);
                bfr[nt] = *(const short8*)&Bs[row * 64 + sl * 8];
            }
#pragma unroll
            for (int mt = 0; mt < 2; ++mt)
#pragma unroll
                for (int nt = 0; nt < 4; ++nt)
                    acc[mt][nt] = __builtin_amdgcn_mfma_f32_16x16x32_bf16(af[mt], bfr[nt], acc[mt][nt], 0, 0, 0);
        }
        __syncthreads();
    }
#pragma unroll
    for (int mt = 0; mt < 2; ++mt) {
#pragma unroll
        for (int i = 0; i < 4; ++i) {
            int gm = m0 + wr * 32 + mt * 16 + lh * 4 + i;
            float mk = 1.f;
            if (EPI == 2) mk = (mask[gm] != 0) ? 1.f : 0.f;
#pragma unroll
            for (int nt = 0; nt < 4; ++nt) {
                int gn = n0 + wc * 64 + nt * 16 + l15;
                float v = acc[mt][nt][i] + bias[gn];
                v = resx[(size_t)gm * N + gn] + v * mk;
                Cout[(size_t)gm * N + gn] = v;
            }
        }
    }
}

// ---------------- fused QKV GEMM (64x128 tiles) + bias + RoPE(+scale) / V-transpose --
__global__ __launch_bounds__(256) void k_qkv64(
    const short* __restrict__ A,
    const short* __restrict__ Wq, const short* __restrict__ Wk, const short* __restrict__ Wv,
    const float* __restrict__ bq, const float* __restrict__ bk, const float* __restrict__ bv,
    const float* __restrict__ ct, const float* __restrict__ st,
    unsigned short* __restrict__ q16, unsigned short* __restrict__ k16,
    unsigned short* __restrict__ vt16) {
    __shared__ __align__(16) short As[64 * 32];
    __shared__ __align__(16) short Bs[128 * 32];
    int mat = blockIdx.y >> 1;
    int n0 = (blockIdx.y & 1) * 128;
    const short* Bt = (mat == 0) ? Wq : (mat == 1) ? Wk : Wv;
    const float* bias = (mat == 0) ? bq : (mat == 1) ? bk : bv;
    int t = threadIdx.x;
    int lane = t & 63, wid = t >> 6;
    int wr = wid >> 1, wc = wid & 1;
    int m0 = blockIdx.x * 64;
    int l15 = lane & 15, lh = lane >> 4;
    f32x4 acc[2][4] = {};
    int srow = t >> 2, sslot = t & 3;
    for (int k0 = 0; k0 < DD; k0 += 32) {
        {
            int sw = sslot ^ ((srow >> 1) & 3);
            *(float4*)&As[srow * 32 + sw * 8] =
                *(const float4*)&A[(size_t)(m0 + srow) * DD + k0 + sslot * 8];
        }
#pragma unroll
        for (int p = 0; p < 2; ++p) {
            int row = srow + p * 64;
            int sw = sslot ^ ((row >> 1) & 3);
            *(float4*)&Bs[row * 32 + sw * 8] =
                *(const float4*)&Bt[(size_t)(n0 + row) * DD + k0 + sslot * 8];
        }
        __syncthreads();
        short8 af[2], bfr[4];
#pragma unroll
        for (int mt = 0; mt < 2; ++mt) {
            int row = wr * 32 + mt * 16 + l15;
            int sl = lh ^ ((row >> 1) & 3);
            af[mt] = *(const short8*)&As[row * 32 + sl * 8];
        }
#pragma unroll
        for (int nt = 0; nt < 4; ++nt) {
            int row = wc * 64 + nt * 16 + l15;
            int sl = lh ^ ((row >> 1) & 3);
            bfr[nt] = *(const short8*)&Bs[row * 32 + sl * 8];
        }
#pragma unroll
        for (int mt = 0; mt < 2; ++mt)
#pragma unroll
            for (int nt = 0; nt < 4; ++nt)
                acc[mt][nt] = __builtin_amdgcn_mfma_f32_16x16x32_bf16(af[mt], bfr[nt], acc[mt][nt], 0, 0, 0);
        __syncthreads();
    }
    float bs[4];
#pragma unroll
    for (int nt = 0; nt < 4; ++nt) bs[nt] = bias[n0 + wc * 64 + nt * 16 + l15];
    if (mat < 2) {
        unsigned short* dst = (mat == 0) ? q16 : k16;
        // Q scale folds 1/sqrt(32) AND log2(e) (flash softmax runs base-2)
        const float qscale = (mat == 0) ? 0.25503486f : 1.f;
#pragma unroll
        for (int mt = 0; mt < 2; ++mt) {
#pragma unroll
            for (int i = 0; i < 4; ++i) {
                int gm = m0 + wr * 32 + mt * 16 + lh * 4 + i;
                int s = gm & (SS - 1);
                float c = ct[s * 16 + l15], sn = st[s * 16 + l15];
                float val[4];
#pragma unroll
                for (int nt = 0; nt < 4; ++nt) val[nt] = (acc[mt][nt][i] + bs[nt]) * qscale;
#pragma unroll
                for (int nt = 0; nt < 4; ++nt) {
                    float partner = val[nt ^ 1];
                    float o = ((nt & 1) == 0) ? (val[nt] * c - partner * sn)
                                              : (val[nt] * c + partner * sn);
                    dst[(size_t)gm * DD + n0 + wc * 64 + nt * 16 + l15] = f2bf(o);
                }
            }
        }
    } else {
#pragma unroll
        for (int mt = 0; mt < 2; ++mt) {
            int gmb = m0 + wr * 32 + mt * 16 + lh * 4;
            int b = gmb >> 9, sb = gmb & (SS - 1);
#pragma unroll
            for (int nt = 0; nt < 4; ++nt) {
                int gn = n0 + wc * 64 + nt * 16 + l15;
                int h = gn >> 5, d = gn & 31;
                ushort4 u;
#pragma unroll
                for (int i = 0; i < 4; ++i)
                    (&u.x)[i] = f2bf(acc[mt][nt][i] + bs[nt]);
                *(ushort4*)&vt16[((size_t)((b * HH + h) * HDIM + d)) * SS + sb] = u;
            }
        }
    }
}

// ---------------- fused flash attention (Q pre-scaled incl. log2e; base-2 softmax) ----
__global__ __launch_bounds__(256) void k_flash(
    const short* __restrict__ qb, const short* __restrict__ kb,
    const short* __restrict__ vt, const int* __restrict__ mask,
    unsigned short* __restrict__ ctxb) {
    __shared__ float bias_lds[SS];
    __shared__ __align__(16) short p_lds[4][32 * 72];
    __shared__ __align__(16) float r_lds[4][32];
    int t = threadIdx.x, lane = t & 63, wq = t >> 6;
    int bh = blockIdx.y;
    int b = bh >> 3, h = bh & 7;
    int q0 = blockIdx.x * 128 + wq * 32;
    bias_lds[t]       = (mask[b * SS + t]       != 0) ? 0.f : -1.0e38f;
    bias_lds[t + 256] = (mask[b * SS + t + 256] != 0) ? 0.f : -1.0e38f;
    __syncthreads();
    int l15 = lane & 15, lh = lane >> 4;
    short8 qfr[2];
    qfr[0] = *(const short8*)&qb[((size_t)(b * SS) + q0 + l15) * DD + h * HDIM + lh * 8];
    qfr[1] = *(const short8*)&qb[((size_t)(b * SS) + q0 + 16 + l15) * DD + h * HDIM + lh * 8];
    float m[2] = {-1.0e38f, -1.0e38f};
    float lsum[2] = {0.f, 0.f};
    f32x4 oacc[2][2] = {};   // [mf = q-frag][df = d-frag]
    for (int k0 = 0; k0 < SS; k0 += 64) {
        f32x4 sT[4][2];
#pragma unroll
        for (int kt = 0; kt < 4; ++kt) {
            short8 kf = *(const short8*)&kb[((size_t)(b * SS) + k0 + kt * 16 + l15) * DD + h * HDIM + lh * 8];
#pragma unroll
            for (int qf = 0; qf < 2; ++qf) {
                f32x4 z = {0.f, 0.f, 0.f, 0.f};
                sT[kt][qf] = __builtin_amdgcn_mfma_f32_16x16x32_bf16(kf, qfr[qf], z, 0, 0, 0);
            }
        }
        float p[2][16];
        float r[2];
#pragma unroll
        for (int qf = 0; qf < 2; ++qf) {
            float pmax = -1.0e38f;
#pragma unroll
            for (int kt = 0; kt < 4; ++kt)
#pragma unroll
                for (int i = 0; i < 4; ++i) {
                    float s = sT[kt][qf][i] + bias_lds[k0 + kt * 16 + lh * 4 + i];
                    p[qf][kt * 4 + i] = s;
                    pmax = fmaxf(pmax, s);
                }
            pmax = fmaxf(pmax, __shfl_xor(pmax, 16));
            pmax = fmaxf(pmax, __shfl_xor(pmax, 32));
            float mn = fmaxf(m[qf], pmax);
            r[qf] = exp2f(m[qf] - mn);
            m[qf] = mn;
            float cs = 0.f;
#pragma unroll
            for (int j = 0; j < 16; ++j) {
                float e = exp2f(p[qf][j] - mn);
                p[qf][j] = e;
                cs += e;
            }
            cs += __shfl_xor(cs, 16);
            cs += __shfl_xor(cs, 32);
            lsum[qf] = lsum[qf] * r[qf] + cs;
        }
#pragma unroll
        for (int qf = 0; qf < 2; ++qf) {
            int qq = qf * 16 + l15;
#pragma unroll
            for (int kt = 0; kt < 4; ++kt) {
                unsigned u0, u1;
                asm("v_cvt_pk_bf16_f32 %0, %1, %2"
                    : "=v"(u0) : "v"(p[qf][kt * 4 + 0]), "v"(p[qf][kt * 4 + 1]));
                asm("v_cvt_pk_bf16_f32 %0, %1, %2"
                    : "=v"(u1) : "v"(p[qf][kt * 4 + 2]), "v"(p[qf][kt * 4 + 3]));
                uint2 u = { u0, u1 };
                *(uint2*)&p_lds[wq][qq * 72 + kt * 16 + lh * 4] = u;
            }
        }
        if (lane < 16) { r_lds[wq][l15] = r[0]; r_lds[wq][16 + l15] = r[1]; }
        __syncthreads();
#pragma unroll
        for (int mf = 0; mf < 2; ++mf) {
            float4 rv = *(const float4*)&r_lds[wq][mf * 16 + lh * 4];
#pragma unroll
            for (int df = 0; df < 2; ++df) {
                oacc[mf][df][0] *= rv.x; oacc[mf][df][1] *= rv.y;
                oacc[mf][df][2] *= rv.z; oacc[mf][df][3] *= rv.w;
            }
        }
#pragma unroll
        for (int ks = 0; ks < 2; ++ks) {
            short8 pa0 = *(const short8*)&p_lds[wq][(l15) * 72 + ks * 32 + lh * 8];
            short8 pa1 = *(const short8*)&p_lds[wq][(16 + l15) * 72 + ks * 32 + lh * 8];
#pragma unroll
            for (int df = 0; df < 2; ++df) {
                short8 vf = *(const short8*)&vt[((size_t)bh * HDIM + df * 16 + l15) * SS + k0 + ks * 32 + lh * 8];
                oacc[0][df] = __builtin_amdgcn_mfma_f32_16x16x32_bf16(pa0, vf, oacc[0][df], 0, 0, 0);
                oacc[1][df] = __builtin_amdgcn_mfma_f32_16x16x32_bf16(pa1, vf, oacc[1][df], 0, 0, 0);
            }
        }
        __syncthreads();
    }
    if (lane < 16) { r_lds[wq][l15] = 1.f / lsum[0]; r_lds[wq][16 + l15] = 1.f / lsum[1]; }
    __syncthreads();
#pragma unroll
    for (int mf = 0; mf < 2; ++mf) {
        float4 lv = *(const float4*)&r_lds[wq][mf * 16 + lh * 4];
        const float li[4] = { lv.x, lv.y, lv.z, lv.w };
#pragma unroll
        for (int df = 0; df < 2; ++df)
#pragma unroll
            for (int i = 0; i < 4; ++i) {
                int gq = q0 + mf * 16 + lh * 4 + i;
                int gd = df * 16 + l15;
                ctxb[((size_t)(b * SS) + gq) * DD + h * HDIM + gd] = f2bf(oacc[mf][df][i] * li[i]);
            }
    }
}

// ---------------- head: fused final-LN + fp32 partial GEMV (nontemporal W) ----------
__global__ __launch_bounds__(256) void k_head_part(
    const float* __restrict__ x, const float* __restrict__ fns, const float* __restrict__ fnb,
    const float* __restrict__ W, float* __restrict__ part) {
    __shared__ float xs[16 * HEAD_KC];
    int c = blockIdx.x;
    int t = threadIdx.x, lane = t & 63, w = t >> 6;
    float4 sv = *(const float4*)&fns[lane * 4];
    float4 bv = *(const float4*)&fnb[lane * 4];
#pragma unroll
    for (int rr = 0; rr < 4; ++rr) {
        int b = w * 4 + rr;
        float4 v = *(const float4*)&x[(size_t)b * SD + c * HEAD_KC + lane * 4];
        float s1 = v.x + v.y + v.z + v.w;
        float s2 = v.x * v.x + v.y * v.y + v.z * v.z + v.w * v.w;
#pragma unroll
        for (int off = 32; off > 0; off >>= 1) {
            s1 += __shfl_xor(s1, off);
            s2 += __shfl_xor(s2, off);
        }
        float mean = s1 * (1.f / DD);
        float var = s2 * (1.f / DD) - mean * mean;
        float rstd = rsqrtf(var + 1e-5f);
        float4 o;
        o.x = (v.x - mean) * rstd * sv.x + bv.x;
        o.y = (v.y - mean) * rstd * sv.y + bv.y;
        o.z = (v.z - mean) * rstd * sv.z + bv.z;
        o.w = (v.w - mean) * rstd * sv.w + bv.w;
        *(float4*)&xs[b * HEAD_KC + lane * 4] = o;
    }
    __syncthreads();
    int k0 = c * HEAD_KC;
    int n4 = t * 4;
    float acc[16][4] = {};
#pragma unroll 8
    for (int k = 0; k < HEAD_KC; ++k) {
        f32x4 wv = __builtin_nontemporal_load((const f32x4*)&W[(size_t)(k0 + k) * NSOUT + n4]);
#pragma unroll
        for (int b = 0; b < 16; ++b) {
            float xv = xs[b * HEAD_KC + k];
            acc[b][0] += xv * wv[0]; acc[b][1] += xv * wv[1];
            acc[b][2] += xv * wv[2]; acc[b][3] += xv * wv[3];
        }
    }
#pragma unroll
    for (int b = 0; b < 16; ++b) {
        float4 o = {acc[b][0], acc[b][1], acc[b][2], acc[b][3]};
        *(float4*)&part[((size_t)c * 16 + b) * NSOUT + n4] = o;
    }
}

// ---------------- head reduce: 64 blocks x 512 threads, 8 c-groups ----------------
__global__ __launch_bounds__(512) void k_head_reduce(
    const float* __restrict__ part, const float* __restrict__ hb,
    float* __restrict__ out) {
    __shared__ float red[8][260];
    int t = threadIdx.x;
    int col = t & 63;            // float4 column within the block's 256-output slice
    int grp = t >> 6;            // 0..7
    int base = blockIdx.x * 256; // 64 blocks x 256 outputs = 16384
    f32x4 s = {0.f, 0.f, 0.f, 0.f};
#pragma unroll 8
    for (int c = grp; c < HEAD_NCH; c += 8) {
        f32x4 p = *(const f32x4*)&part[(size_t)c * (16 * NSOUT) + base + col * 4];
        s[0] += p[0]; s[1] += p[1]; s[2] += p[2]; s[3] += p[3];
    }
    red[grp][col * 4 + 0] = s[0];
    red[grp][col * 4 + 1] = s[1];
    red[grp][col * 4 + 2] = s[2];
    red[grp][col * 4 + 3] = s[3];
    __syncthreads();
    if (t < 256) {
        float acc = 0.f;
#pragma unroll
        for (int g = 0; g < 8; ++g) acc += red[g][t];
        out[base + t] = acc + hb[(base + t) & (NSOUT - 1)];
    }
}

extern "C" void kernel_launch(void* const* d_in, const int* in_sizes, int n_in,
                              void* d_out, int out_size, void* d_ws, size_t ws_size,
                              hipStream_t stream) {
    const float* values = (const float*)d_in[0];
    const float* dib    = (const float*)d_in[1];
    const float* gamma  = (const float*)d_in[2];
    const float* mtyp   = (const float*)d_in[3];
    const int*   mask   = (const int*)d_in[4];
    const float* in_w   = (const float*)d_in[5];
    const float* in_b   = (const float*)d_in[6];
    const float* ln1_s  = (const float*)d_in[7];
    const float* ln1_b  = (const float*)d_in[8];
    const float* p_qw   = (const float*)d_in[9];
    const float* p_qb   = (const float*)d_in[10];
    const float* p_kw   = (const float*)d_in[11];
    const float* p_kb   = (const float*)d_in[12];
    const float* p_vw   = (const float*)d_in[13];
    const float* p_vb   = (const float*)d_in[14];
    const float* p_ow   = (const float*)d_in[15];
    const float* p_ob   = (const float*)d_in[16];
    const float* ln2_s  = (const float*)d_in[17];
    const float* ln2_b  = (const float*)d_in[18];
    const float* p_f1w  = (const float*)d_in[19];
    const float* p_f1b  = (const float*)d_in[20];
    const float* p_f2w  = (const float*)d_in[21];
    const float* p_f2b  = (const float*)d_in[22];
    const float* fn_s   = (const float*)d_in[23];
    const float* fn_b   = (const float*)d_in[24];
    const float* head_w = (const float*)d_in[25];
    const float* head_b = (const float*)d_in[26];
    float* out = (float*)d_out;

    const size_t MB = 1u << 20;
    char* w = (char*)d_ws;
    float* x    = (float*)(w + 0 * MB);            // 8 MB fp32 residual stream
    unsigned short* h16  = (unsigned short*)(w + 32 * MB);  // 4 MB each
    unsigned short* q16  = (unsigned short*)(w + 36 * MB);
    unsigned short* k16  = (unsigned short*)(w + 40 * MB);
    unsigned short* vt16 = (unsigned short*)(w + 44 * MB);
    unsigned short* cx16 = (unsigned short*)(w + 48 * MB);
    unsigned short* f116 = (unsigned short*)(w + 52 * MB);  // 16 MB
    unsigned short* wq16 = (unsigned short*)(w + 68 * MB);  // 256 KB each (2 layers)
    unsigned short* wk16 = (unsigned short*)(w + 68 * MB + 256 * 1024);
    unsigned short* wv16 = (unsigned short*)(w + 68 * MB + 512 * 1024);
    unsigned short* wo16 = (unsigned short*)(w + 68 * MB + 768 * 1024);
    unsigned short* wf116 = (unsigned short*)(w + 69 * MB); // 1 MB
    unsigned short* wf216 = (unsigned short*)(w + 70 * MB); // 1 MB
    float* ct   = (float*)(w + 71 * MB);
    float* st   = (float*)(w + 71 * MB + 64 * 1024);
    float* sc   = (float*)(w + 72 * MB);           // head partials (33.5 MB)

    k_prep_all<<<3616, 256, 0, stream>>>(p_qw, p_kw, p_vw, p_ow, p_f1w, p_f2w,
                                         wq16, wk16, wv16, wo16, wf116, wf216, ct, st,
                                         values, dib, gamma, mtyp, in_w, in_b, x);

    for (int l = 0; l < NL; ++l) {
        k_layernorm_w<true><<<2048, 256, 0, stream>>>(x, h16, ln1_s + l * DD, ln1_b + l * DD);
        k_qkv64<<<dim3(128, 6), 256, 0, stream>>>((const short*)h16,
            (const short*)(wq16 + l * 65536), (const short*)(wk16 + l * 65536),
            (const short*)(wv16 + l * 65536),
            p_qb + l * DD, p_kb + l * DD, p_vb + l * DD, ct, st, q16, k16, vt16);
        k_flash<<<dim3(4, BB * HH), 256, 0, stream>>>((const short*)q16, (const short*)k16,
            (const short*)vt16, mask, cx16);
        k_gemm64<2><<<dim3(128, 2), 256, 0, stream>>>((const short*)cx16,
            (const short*)(wo16 + l * 65536), p_ob + l * DD, x, ROWS, DD, DD, x, mask);
        k_layernorm_w<true><<<2048, 256, 0, stream>>>(x, h16, ln2_s + l * DD, ln2_b + l * DD);
        k_gemm_ff1<<<dim3(64, 8), 256, 0, stream>>>((const short*)h16,
            (const short*)(wf116 + l * 262144), p_f1b + l * FFD, f116, ROWS, FFD, DD);
        k_gemm64<3><<<dim3(128, 2), 256, 0, stream>>>((const short*)f116,
            (const short*)(wf216 + l * 262144), p_f2b + l * DD, x, ROWS, DD, FFD, x, nullptr);
    }

    k_head_part<<<HEAD_NCH, 256, 0, stream>>>(x, fn_s, fn_b, head_w, sc);
    k_head_reduce<<<64, 512, 0, stream>>>(sc, head_b, out);
}

// Round 13
// 348.201 us; speedup vs baseline: 1.1146x; 1.1146x over previous
//
#include <hip/hip_runtime.h>
#include <math.h>

#define BB 16
#define SS 512
#define DD 256
#define HH 8
#define HDIM 32
#define FFD 1024
#define NL 2
#define NSOUT 1024
#define SD (SS*DD)      // 131072
#define ROWS (BB*SS)    // 8192

#define HEAD_KC 256
#define HEAD_NCH 512    // SD / HEAD_KC

typedef __attribute__((ext_vector_type(8))) short short8;
typedef __attribute__((ext_vector_type(4))) float f32x4;

__device__ __forceinline__ unsigned short f2bf(float f) {
    union { float f; unsigned u; } c; c.f = f;
    unsigned u = c.u + 0x7fffu + ((c.u >> 16) & 1u);
    return (unsigned short)(u >> 16);
}

// ------- one-shot prep: weight transposes + rope tables + input projection -------
__global__ __launch_bounds__(256) void k_prep_all(
    const float* __restrict__ p_qw, const float* __restrict__ p_kw,
    const float* __restrict__ p_vw, const float* __restrict__ p_ow,
    const float* __restrict__ p_f1w, const float* __restrict__ p_f2w,
    unsigned short* __restrict__ wq, unsigned short* __restrict__ wk,
    unsigned short* __restrict__ wv, unsigned short* __restrict__ wo,
    unsigned short* __restrict__ wf1, unsigned short* __restrict__ wf2,
    float* __restrict__ ct, float* __restrict__ st,
    const float* __restrict__ values, const float* __restrict__ dib,
    const float* __restrict__ gamma, const float* __restrict__ mtyp,
    const float* __restrict__ in_w, const float* __restrict__ in_b,
    float* __restrict__ x) {
    int bid = blockIdx.x;
    int t = threadIdx.x;
    if (bid >= 1568) {   // input projection: 2048 blocks
        int i = (bid - 1568) * 256 + t;   // ROWS*64
        int row = i >> 6, d4 = (i & 63) * 4;
        float v = values[row];
        float f0 = (v >= 0.f) ? 1.f : -1.f;
        float f1 = fabsf(v);
        float f2 = gamma[row];
        float f3 = dib[row];
        float f4 = mtyp[row] * 2.f - 1.f;
        float4 w0 = *(const float4*)&in_w[d4];
        float4 w1 = *(const float4*)&in_w[DD + d4];
        float4 w2 = *(const float4*)&in_w[2 * DD + d4];
        float4 w3 = *(const float4*)&in_w[3 * DD + d4];
        float4 w4 = *(const float4*)&in_w[4 * DD + d4];
        float4 bb = *(const float4*)&in_b[d4];
        float4 o;
        o.x = f0 * w0.x + f1 * w1.x + f2 * w2.x + f3 * w3.x + f4 * w4.x + bb.x;
        o.y = f0 * w0.y + f1 * w1.y + f2 * w2.y + f3 * w3.y + f4 * w4.y + bb.y;
        o.z = f0 * w0.z + f1 * w1.z + f2 * w2.z + f3 * w3.z + f4 * w4.z + bb.z;
        o.w = f0 * w0.w + f1 * w1.w + f2 * w2.w + f3 * w3.w + f4 * w4.w + bb.w;
        *(float4*)&x[(size_t)row * DD + d4] = o;
        return;
    }
    if (bid >= 1536) {   // rope tables
        int i = (bid - 1536) * 256 + t;
        if (i < SS * 16) {
            int s = i >> 4, f = i & 15;
            float invf = powf(10000.f, -(float)f / 16.f);
            float ang = (float)s * invf;
            ct[i] = cosf(ang);
            st[i] = sinf(ang);
        }
        return;
    }
    const float* src; unsigned short* dst;
    int K, N, kx, nx, l;
    if (bid < 512) {
        int grp = bid >> 7, r = bid & 127; l = r >> 6; int tl = r & 63;
        kx = tl >> 3; nx = tl & 7; K = DD; N = DD;
        src = grp == 0 ? p_qw : grp == 1 ? p_kw : grp == 2 ? p_vw : p_ow;
        dst = grp == 0 ? wq : grp == 1 ? wk : grp == 2 ? wv : wo;
    } else if (bid < 1024) {
        int r = bid - 512; l = r >> 8; int tl = r & 255;
        kx = tl >> 5; nx = tl & 31; K = DD; N = FFD; src = p_f1w; dst = wf1;
    } else {
        int r = bid - 1024; l = r >> 8; int tl = r & 255;
        kx = tl >> 3; nx = tl & 7; K = FFD; N = DD; src = p_f2w; dst = wf2;
    }
    __shared__ float tile[32][33];
    size_t zo = (size_t)l * K * N;
    int k0 = kx * 32, n0 = nx * 32;
    int r_ = t >> 3, c4 = (t & 7) * 4;
    float4 a = *(const float4*)&src[zo + (size_t)(k0 + r_) * N + n0 + c4];
    tile[r_][c4 + 0] = a.x; tile[r_][c4 + 1] = a.y; tile[r_][c4 + 2] = a.z; tile[r_][c4 + 3] = a.w;
    __syncthreads();
    unsigned o0 = f2bf(tile[c4 + 0][r_]), o1 = f2bf(tile[c4 + 1][r_]);
    unsigned o2 = f2bf(tile[c4 + 2][r_]), o3 = f2bf(tile[c4 + 3][r_]);
    uint2 ud = { o0 | (o1 << 16), o2 | (o3 << 16) };
    *(uint2*)&dst[zo + (size_t)(n0 + r_) * K + k0 + c4] = ud;
}

// ---------------- wave-per-row layernorm over D=256, no barriers ----------------
template <bool OBF>
__global__ __launch_bounds__(256) void k_layernorm_w(
    const float* __restrict__ in, void* __restrict__ outp,
    const float* __restrict__ sc, const float* __restrict__ bi) {
    int t = threadIdx.x, lane = t & 63, w = t >> 6;
    int row = blockIdx.x * 4 + w;
    float4 v = *(const float4*)&in[(size_t)row * DD + lane * 4];
    float s1 = v.x + v.y + v.z + v.w;
    float s2 = v.x * v.x + v.y * v.y + v.z * v.z + v.w * v.w;
#pragma unroll
    for (int off = 32; off > 0; off >>= 1) {
        s1 += __shfl_xor(s1, off);
        s2 += __shfl_xor(s2, off);
    }
    float mean = s1 * (1.f / DD);
    float var = s2 * (1.f / DD) - mean * mean;
    float rstd = rsqrtf(var + 1e-5f);
    float4 sv = *(const float4*)&sc[lane * 4];
    float4 bv = *(const float4*)&bi[lane * 4];
    float o0 = (v.x - mean) * rstd * sv.x + bv.x;
    float o1 = (v.y - mean) * rstd * sv.y + bv.y;
    float o2 = (v.z - mean) * rstd * sv.z + bv.z;
    float o3 = (v.w - mean) * rstd * sv.w + bv.w;
    if (OBF) {
        ushort4 u = { f2bf(o0), f2bf(o1), f2bf(o2), f2bf(o3) };
        *(ushort4*)&((unsigned short*)outp)[(size_t)row * DD + lane * 4] = u;
    } else {
        float4 o = { o0, o1, o2, o3 };
        *(float4*)&((float*)outp)[(size_t)row * DD + lane * 4] = o;
    }
}

// ---------------- bf16 MFMA GEMM 128x128 (FF1): C = A@Bt^T + bias, exact GELU, bf16 out
__global__ __launch_bounds__(256) void k_gemm_ff1(
    const short* __restrict__ A, const short* __restrict__ Bt,
    const float* __restrict__ bias, unsigned short* __restrict__ Cout,
    int M, int N, int K) {
    __shared__ __align__(16) short As[128 * 32];
    __shared__ __align__(16) short Bs[128 * 32];
    int t = threadIdx.x;
    int lane = t & 63, wid = t >> 6;
    int wr = wid >> 1, wc = wid & 1;
    int m0 = blockIdx.x * 128, n0 = blockIdx.y * 128;
    f32x4 acc[4][4] = {};
    int srow = t >> 2, sslot = t & 3;
    for (int k0 = 0; k0 < K; k0 += 32) {
#pragma unroll
        for (int p = 0; p < 2; ++p) {
            int row = srow + p * 64;
            int sw = sslot ^ ((row >> 1) & 3);
            *(float4*)&As[row * 32 + sw * 8] =
                *(const float4*)&A[(size_t)(m0 + row) * K + k0 + sslot * 8];
            *(float4*)&Bs[row * 32 + sw * 8] =
                *(const float4*)&Bt[(size_t)(n0 + row) * K + k0 + sslot * 8];
        }
        __syncthreads();
        short8 af[4], bfr[4];
#pragma unroll
        for (int mt = 0; mt < 4; ++mt) {
            int row = wr * 64 + mt * 16 + (lane & 15);
            int sl = (lane >> 4) ^ ((row >> 1) & 3);
            af[mt] = *(const short8*)&As[row * 32 + sl * 8];
        }
#pragma unroll
        for (int nt = 0; nt < 4; ++nt) {
            int row = wc * 64 + nt * 16 + (lane & 15);
            int sl = (lane >> 4) ^ ((row >> 1) & 3);
            bfr[nt] = *(const short8*)&Bs[row * 32 + sl * 8];
        }
#pragma unroll
        for (int mt = 0; mt < 4; ++mt)
#pragma unroll
            for (int nt = 0; nt < 4; ++nt)
                acc[mt][nt] = __builtin_amdgcn_mfma_f32_16x16x32_bf16(af[mt], bfr[nt], acc[mt][nt], 0, 0, 0);
        __syncthreads();
    }
#pragma unroll
    for (int mt = 0; mt < 4; ++mt) {
#pragma unroll
        for (int i = 0; i < 4; ++i) {
            int gm = m0 + wr * 64 + mt * 16 + (lane >> 4) * 4 + i;
#pragma unroll
            for (int nt = 0; nt < 4; ++nt) {
                int gn = n0 + wc * 64 + nt * 16 + (lane & 15);
                float v = acc[mt][nt][i] + bias[gn];
                v = 0.5f * v * (1.f + erff(v * 0.70710678118654752f));
                Cout[(size_t)gm * N + gn] = f2bf(v);
            }
        }
    }
}

// ---------------- bf16 MFMA GEMM 64x128, K_STEP=64 (O-proj / FF2), fp32 residual out
template <int EPI>
__global__ __launch_bounds__(256) void k_gemm64(
    const short* __restrict__ A, const short* __restrict__ Bt,
    const float* __restrict__ bias, float* __restrict__ Cout,
    int M, int N, int K, const float* __restrict__ resx, const int* __restrict__ mask) {
    __shared__ __align__(16) short As[64 * 64];    // 8 KB
    __shared__ __align__(16) short Bs[128 * 64];   // 16 KB
    int t = threadIdx.x;
    int lane = t & 63, wid = t >> 6;
    int wr = wid >> 1, wc = wid & 1;          // wave: 32 rows x 64 cols
    int m0 = blockIdx.x * 64, n0 = blockIdx.y * 128;
    int l15 = lane & 15, lh = lane >> 4;
    f32x4 acc[2][4] = {};
    for (int k0 = 0; k0 < K; k0 += 64) {
#pragma unroll
        for (int p = 0; p < 2; ++p) {
            int idx = t + p * 256;
            int row = idx >> 3, sl = idx & 7;
            int sw = sl ^ (row & 7);
            *(float4*)&As[row * 64 + sw * 8] =
                *(const float4*)&A[(size_t)(m0 + row) * K + k0 + sl * 8];
        }
#pragma unroll
        for (int p = 0; p < 4; ++p) {
            int idx = t + p * 256;
            int row = idx >> 3, sl = idx & 7;
            int sw = sl ^ (row & 7);
            *(float4*)&Bs[row * 64 + sw * 8] =
                *(const float4*)&Bt[(size_t)(n0 + row) * K + k0 + sl * 8];
        }
        __syncthreads();
#pragma unroll
        for (int kk = 0; kk < 2; ++kk) {
            short8 af[2], bfr[4];
#pragma unroll
            for (int mt = 0; mt < 2; ++mt) {
                int row = wr * 32 + mt * 16 + l15;
                int sl = (kk * 4 + lh) ^ (row & 7);
                af[mt] = *(const short8*)&As[row * 64 + sl * 8];
            }
#pragma unroll
            for (int nt = 0; nt < 4; ++nt) {
                int row = wc * 64 + nt * 16 + l15;
                int sl = (kk * 4 + lh) ^ (row & 7);
                bfr[nt] = *(const short8*)&Bs[row * 64 + sl * 8];
            }
#pragma unroll
            for (int mt = 0; mt < 2; ++mt)
#pragma unroll
                for (int nt = 0; nt < 4; ++nt)
                    acc[mt][nt] = __builtin_amdgcn_mfma_f32_16x16x32_bf16(af[mt], bfr[nt], acc[mt][nt], 0, 0, 0);
        }
        __syncthreads();
    }
#pragma unroll
    for (int mt = 0; mt < 2; ++mt) {
#pragma unroll
        for (int i = 0; i < 4; ++i) {
            int gm = m0 + wr * 32 + mt * 16 + lh * 4 + i;
            float mk = 1.f;
            if (EPI == 2) mk = (mask[gm] != 0) ? 1.f : 0.f;
#pragma unroll
            for (int nt = 0; nt < 4; ++nt) {
                int gn = n0 + wc * 64 + nt * 16 + l15;
                float v = acc[mt][nt][i] + bias[gn];
                v = resx[(size_t)gm * N + gn] + v * mk;
                Cout[(size_t)gm * N + gn] = v;
            }
        }
    }
}

// ---------------- fused QKV GEMM (64x128 tiles) + bias + RoPE(+scale) / V-transpose --
__global__ __launch_bounds__(256) void k_qkv64(
    const short* __restrict__ A,
    const short* __restrict__ Wq, const short* __restrict__ Wk, const short* __restrict__ Wv,
    const float* __restrict__ bq, const float* __restrict__ bk, const float* __restrict__ bv,
    const float* __restrict__ ct, const float* __restrict__ st,
    unsigned short* __restrict__ q16, unsigned short* __restrict__ k16,
    unsigned short* __restrict__ vt16) {
    __shared__ __align__(16) short As[64 * 32];
    __shared__ __align__(16) short Bs[128 * 32];
    int mat = blockIdx.y >> 1;
    int n0 = (blockIdx.y & 1) * 128;
    const short* Bt = (mat == 0) ? Wq : (mat == 1) ? Wk : Wv;
    const float* bias = (mat == 0) ? bq : (mat == 1) ? bk : bv;
    int t = threadIdx.x;
    int lane = t & 63, wid = t >> 6;
    int wr = wid >> 1, wc = wid & 1;
    int m0 = blockIdx.x * 64;
    int l15 = lane & 15, lh = lane >> 4;
    f32x4 acc[2][4] = {};
    int srow = t >> 2, sslot = t & 3;
    for (int k0 = 0; k0 < DD; k0 += 32) {
        {
            int sw = sslot ^ ((srow >> 1) & 3);
            *(float4*)&As[srow * 32 + sw * 8] =
                *(const float4*)&A[(size_t)(m0 + srow) * DD + k0 + sslot * 8];
        }
#pragma unroll
        for (int p = 0; p < 2; ++p) {
            int row = srow + p * 64;
            int sw = sslot ^ ((row >> 1) & 3);
            *(float4*)&Bs[row * 32 + sw * 8] =
                *(const float4*)&Bt[(size_t)(n0 + row) * DD + k0 + sslot * 8];
        }
        __syncthreads();
        short8 af[2], bfr[4];
#pragma unroll
        for (int mt = 0; mt < 2; ++mt) {
            int row = wr * 32 + mt * 16 + l15;
            int sl = lh ^ ((row >> 1) & 3);
            af[mt] = *(const short8*)&As[row * 32 + sl * 8];
        }
#pragma unroll
        for (int nt = 0; nt < 4; ++nt) {
            int row = wc * 64 + nt * 16 + l15;
            int sl = lh ^ ((row >> 1) & 3);
            bfr[nt] = *(const short8*)&Bs[row * 32 + sl * 8];
        }
#pragma unroll
        for (int mt = 0; mt < 2; ++mt)
#pragma unroll
            for (int nt = 0; nt < 4; ++nt)
                acc[mt][nt] = __builtin_amdgcn_mfma_f32_16x16x32_bf16(af[mt], bfr[nt], acc[mt][nt], 0, 0, 0);
        __syncthreads();
    }
    float bs[4];
#pragma unroll
    for (int nt = 0; nt < 4; ++nt) bs[nt] = bias[n0 + wc * 64 + nt * 16 + l15];
    if (mat < 2) {
        unsigned short* dst = (mat == 0) ? q16 : k16;
        // Q scale folds 1/sqrt(32) AND log2(e): flash softmax runs base-2
        const float qscale = (mat == 0) ? 0.25503486f : 1.f;
#pragma unroll
        for (int mt = 0; mt < 2; ++mt) {
#pragma unroll
            for (int i = 0; i < 4; ++i) {
                int gm = m0 + wr * 32 + mt * 16 + lh * 4 + i;
                int s = gm & (SS - 1);
                float c = ct[s * 16 + l15], sn = st[s * 16 + l15];
                float val[4];
#pragma unroll
                for (int nt = 0; nt < 4; ++nt) val[nt] = (acc[mt][nt][i] + bs[nt]) * qscale;
#pragma unroll
                for (int nt = 0; nt < 4; ++nt) {
                    float partner = val[nt ^ 1];
                    float o = ((nt & 1) == 0) ? (val[nt] * c - partner * sn)
                                              : (val[nt] * c + partner * sn);
                    dst[(size_t)gm * DD + n0 + wc * 64 + nt * 16 + l15] = f2bf(o);
                }
            }
        }
    } else {
#pragma unroll
        for (int mt = 0; mt < 2; ++mt) {
            int gmb = m0 + wr * 32 + mt * 16 + lh * 4;
            int b = gmb >> 9, sb = gmb & (SS - 1);
#pragma unroll
            for (int nt = 0; nt < 4; ++nt) {
                int gn = n0 + wc * 64 + nt * 16 + l15;
                int h = gn >> 5, d = gn & 31;
                ushort4 u;
#pragma unroll
                for (int i = 0; i < 4; ++i)
                    (&u.x)[i] = f2bf(acc[mt][nt][i] + bs[nt]);
                *(ushort4*)&vt16[((size_t)((b * HH + h) * HDIM + d)) * SS + sb] = u;
            }
        }
    }
}

// ---------------- fused flash attention (Q pre-scaled incl. log2e; base-2 softmax) ----
__global__ __launch_bounds__(256) void k_flash(
    const short* __restrict__ qb, const short* __restrict__ kb,
    const short* __restrict__ vt, const int* __restrict__ mask,
    unsigned short* __restrict__ ctxb) {
    __shared__ float bias_lds[SS];
    __shared__ __align__(16) short p_lds[4][32 * 72];
    __shared__ __align__(16) float r_lds[4][32];
    int t = threadIdx.x, lane = t & 63, wq = t >> 6;
    int bh = blockIdx.y;
    int b = bh >> 3, h = bh & 7;
    int q0 = blockIdx.x * 128 + wq * 32;
    bias_lds[t]       = (mask[b * SS + t]       != 0) ? 0.f : -1.0e38f;
    bias_lds[t + 256] = (mask[b * SS + t + 256] != 0) ? 0.f : -1.0e38f;
    __syncthreads();
    int l15 = lane & 15, lh = lane >> 4;
    short8 qfr[2];
    qfr[0] = *(const short8*)&qb[((size_t)(b * SS) + q0 + l15) * DD + h * HDIM + lh * 8];
    qfr[1] = *(const short8*)&qb[((size_t)(b * SS) + q0 + 16 + l15) * DD + h * HDIM + lh * 8];
    float m[2] = {-1.0e38f, -1.0e38f};
    float lsum[2] = {0.f, 0.f};
    f32x4 oacc[2][2] = {};   // [mf = q-frag][df = d-frag]
    for (int k0 = 0; k0 < SS; k0 += 64) {
        f32x4 sT[4][2];
#pragma unroll
        for (int kt = 0; kt < 4; ++kt) {
            short8 kf = *(const short8*)&kb[((size_t)(b * SS) + k0 + kt * 16 + l15) * DD + h * HDIM + lh * 8];
#pragma unroll
            for (int qf = 0; qf < 2; ++qf) {
                f32x4 z = {0.f, 0.f, 0.f, 0.f};
                sT[kt][qf] = __builtin_amdgcn_mfma_f32_16x16x32_bf16(kf, qfr[qf], z, 0, 0, 0);
            }
        }
        float p[2][16];
        float r[2];
#pragma unroll
        for (int qf = 0; qf < 2; ++qf) {
            float pmax = -1.0e38f;
#pragma unroll
            for (int kt = 0; kt < 4; ++kt)
#pragma unroll
                for (int i = 0; i < 4; ++i) {
                    float s = sT[kt][qf][i] + bias_lds[k0 + kt * 16 + lh * 4 + i];
                    p[qf][kt * 4 + i] = s;
                    pmax = fmaxf(pmax, s);
                }
            pmax = fmaxf(pmax, __shfl_xor(pmax, 16));
            pmax = fmaxf(pmax, __shfl_xor(pmax, 32));
            float mn = fmaxf(m[qf], pmax);
            r[qf] = exp2f(m[qf] - mn);
            m[qf] = mn;
            float cs = 0.f;
#pragma unroll
            for (int j = 0; j < 16; ++j) {
                float e = exp2f(p[qf][j] - mn);
                p[qf][j] = e;
                cs += e;
            }
            cs += __shfl_xor(cs, 16);
            cs += __shfl_xor(cs, 32);
            lsum[qf] = lsum[qf] * r[qf] + cs;
        }
#pragma unroll
        for (int qf = 0; qf < 2; ++qf) {
            int qq = qf * 16 + l15;
#pragma unroll
            for (int kt = 0; kt < 4; ++kt) {
                unsigned u0 = (unsigned)f2bf(p[qf][kt * 4 + 0]) | ((unsigned)f2bf(p[qf][kt * 4 + 1]) << 16);
                unsigned u1 = (unsigned)f2bf(p[qf][kt * 4 + 2]) | ((unsigned)f2bf(p[qf][kt * 4 + 3]) << 16);
                uint2 u = { u0, u1 };
                *(uint2*)&p_lds[wq][qq * 72 + kt * 16 + lh * 4] = u;
            }
        }
        if (lane < 16) { r_lds[wq][l15] = r[0]; r_lds[wq][16 + l15] = r[1]; }
        __syncthreads();
#pragma unroll
        for (int mf = 0; mf < 2; ++mf) {
            float4 rv = *(const float4*)&r_lds[wq][mf * 16 + lh * 4];
#pragma unroll
            for (int df = 0; df < 2; ++df) {
                oacc[mf][df][0] *= rv.x; oacc[mf][df][1] *= rv.y;
                oacc[mf][df][2] *= rv.z; oacc[mf][df][3] *= rv.w;
            }
        }
#pragma unroll
        for (int ks = 0; ks < 2; ++ks) {
            short8 pa0 = *(const short8*)&p_lds[wq][(l15) * 72 + ks * 32 + lh * 8];
            short8 pa1 = *(const short8*)&p_lds[wq][(16 + l15) * 72 + ks * 32 + lh * 8];
#pragma unroll
            for (int df = 0; df < 2; ++df) {
                short8 vf = *(const short8*)&vt[((size_t)bh * HDIM + df * 16 + l15) * SS + k0 + ks * 32 + lh * 8];
                oacc[0][df] = __builtin_amdgcn_mfma_f32_16x16x32_bf16(pa0, vf, oacc[0][df], 0, 0, 0);
                oacc[1][df] = __builtin_amdgcn_mfma_f32_16x16x32_bf16(pa1, vf, oacc[1][df], 0, 0, 0);
            }
        }
        __syncthreads();
    }
    if (lane < 16) { r_lds[wq][l15] = 1.f / lsum[0]; r_lds[wq][16 + l15] = 1.f / lsum[1]; }
    __syncthreads();
#pragma unroll
    for (int mf = 0; mf < 2; ++mf) {
        float4 lv = *(const float4*)&r_lds[wq][mf * 16 + lh * 4];
        const float li[4] = { lv.x, lv.y, lv.z, lv.w };
#pragma unroll
        for (int df = 0; df < 2; ++df)
#pragma unroll
            for (int i = 0; i < 4; ++i) {
                int gq = q0 + mf * 16 + lh * 4 + i;
                int gd = df * 16 + l15;
                ctxb[((size_t)(b * SS) + gq) * DD + h * HDIM + gd] = f2bf(oacc[mf][df][i] * li[i]);
            }
    }
}

// ---------------- head: fused final-LN + fp32 partial GEMV (nontemporal W) ----------
__global__ __launch_bounds__(256) void k_head_part(
    const float* __restrict__ x, const float* __restrict__ fns, const float* __restrict__ fnb,
    const float* __restrict__ W, float* __restrict__ part) {
    __shared__ float xs[16 * HEAD_KC];
    int c = blockIdx.x;
    int t = threadIdx.x, lane = t & 63, w = t >> 6;
    float4 sv = *(const float4*)&fns[lane * 4];
    float4 bv = *(const float4*)&fnb[lane * 4];
#pragma unroll
    for (int rr = 0; rr < 4; ++rr) {
        int b = w * 4 + rr;
        float4 v = *(const float4*)&x[(size_t)b * SD + c * HEAD_KC + lane * 4];
        float s1 = v.x + v.y + v.z + v.w;
        float s2 = v.x * v.x + v.y * v.y + v.z * v.z + v.w * v.w;
#pragma unroll
        for (int off = 32; off > 0; off >>= 1) {
            s1 += __shfl_xor(s1, off);
            s2 += __shfl_xor(s2, off);
        }
        float mean = s1 * (1.f / DD);
        float var = s2 * (1.f / DD) - mean * mean;
        float rstd = rsqrtf(var + 1e-5f);
        float4 o;
        o.x = (v.x - mean) * rstd * sv.x + bv.x;
        o.y = (v.y - mean) * rstd * sv.y + bv.y;
        o.z = (v.z - mean) * rstd * sv.z + bv.z;
        o.w = (v.w - mean) * rstd * sv.w + bv.w;
        *(float4*)&xs[b * HEAD_KC + lane * 4] = o;
    }
    __syncthreads();
    int k0 = c * HEAD_KC;
    int n4 = t * 4;
    float acc[16][4] = {};
#pragma unroll 8
    for (int k = 0; k < HEAD_KC; ++k) {
        f32x4 wv = __builtin_nontemporal_load((const f32x4*)&W[(size_t)(k0 + k) * NSOUT + n4]);
#pragma unroll
        for (int b = 0; b < 16; ++b) {
            float xv = xs[b * HEAD_KC + k];
            acc[b][0] += xv * wv[0]; acc[b][1] += xv * wv[1];
            acc[b][2] += xv * wv[2]; acc[b][3] += xv * wv[3];
        }
    }
#pragma unroll
    for (int b = 0; b < 16; ++b) {
        float4 o = {acc[b][0], acc[b][1], acc[b][2], acc[b][3]};
        *(float4*)&part[((size_t)c * 16 + b) * NSOUT + n4] = o;
    }
}

// ---------------- head reduce: 64 blocks x 512 threads, 8 c-groups ----------------
__global__ __launch_bounds__(512) void k_head_reduce(
    const float* __restrict__ part, const float* __restrict__ hb,
    float* __restrict__ out) {
    __shared__ float red[8][260];
    int t = threadIdx.x;
    int col = t & 63;            // float4 column within the block's 256-output slice
    int grp = t >> 6;            // 0..7
    int base = blockIdx.x * 256; // 64 blocks x 256 outputs = 16384
    f32x4 s = {0.f, 0.f, 0.f, 0.f};
#pragma unroll 8
    for (int c = grp; c < HEAD_NCH; c += 8) {
        f32x4 p = *(const f32x4*)&part[(size_t)c * (16 * NSOUT) + base + col * 4];
        s[0] += p[0]; s[1] += p[1]; s[2] += p[2]; s[3] += p[3];
    }
    red[grp][col * 4 + 0] = s[0];
    red[grp][col * 4 + 1] = s[1];
    red[grp][col * 4 + 2] = s[2];
    red[grp][col * 4 + 3] = s[3];
    __syncthreads();
    if (t < 256) {
        float acc = 0.f;
#pragma unroll
        for (int g = 0; g < 8; ++g) acc += red[g][t];
        out[base + t] = acc + hb[(base + t) & (NSOUT - 1)];
    }
}

extern "C" void kernel_launch(void* const* d_in, const int* in_sizes, int n_in,
                              void* d_out, int out_size, void* d_ws, size_t ws_size,
                              hipStream_t stream) {
    const float* values = (const float*)d_in[0];
    const float* dib    = (const float*)d_in[1];
    const float* gamma  = (const float*)d_in[2];
    const float* mtyp   = (const float*)d_in[3];
    const int*   mask   = (const int*)d_in[4];
    const float* in_w   = (const float*)d_in[5];
    const float* in_b   = (const float*)d_in[6];
    const float* ln1_s  = (const float*)d_in[7];
    const float* ln1_b  = (const float*)d_in[8];
    const float* p_qw   = (const float*)d_in[9];
    const float* p_qb   = (const float*)d_in[10];
    const float* p_kw   = (const float*)d_in[11];
    const float* p_kb   = (const float*)d_in[12];
    const float* p_vw   = (const float*)d_in[13];
    const float* p_vb   = (const float*)d_in[14];
    const float* p_ow   = (const float*)d_in[15];
    const float* p_ob   = (const float*)d_in[16];
    const float* ln2_s  = (const float*)d_in[17];
    const float* ln2_b  = (const float*)d_in[18];
    const float* p_f1w  = (const float*)d_in[19];
    const float* p_f1b  = (const float*)d_in[20];
    const float* p_f2w  = (const float*)d_in[21];
    const float* p_f2b  = (const float*)d_in[22];
    const float* fn_s   = (const float*)d_in[23];
    const float* fn_b   = (const float*)d_in[24];
    const float* head_w = (const float*)d_in[25];
    const float* head_b = (const float*)d_in[26];
    float* out = (float*)d_out;

    const size_t MB = 1u << 20;
    char* w = (char*)d_ws;
    float* x    = (float*)(w + 0 * MB);            // 8 MB fp32 residual stream
    unsigned short* h16  = (unsigned short*)(w + 32 * MB);  // 4 MB each
    unsigned short* q16  = (unsigned short*)(w + 36 * MB);
    unsigned short* k16  = (unsigned short*)(w + 40 * MB);
    unsigned short* vt16 = (unsigned short*)(w + 44 * MB);
    unsigned short* cx16 = (unsigned short*)(w + 48 * MB);
    unsigned short* f116 = (unsigned short*)(w + 52 * MB);  // 16 MB
    unsigned short* wq16 = (unsigned short*)(w + 68 * MB);  // 256 KB each (2 layers)
    unsigned short* wk16 = (unsigned short*)(w + 68 * MB + 256 * 1024);
    unsigned short* wv16 = (unsigned short*)(w + 68 * MB + 512 * 1024);
    unsigned short* wo16 = (unsigned short*)(w + 68 * MB + 768 * 1024);
    unsigned short* wf116 = (unsigned short*)(w + 69 * MB); // 1 MB
    unsigned short* wf216 = (unsigned short*)(w + 70 * MB); // 1 MB
    float* ct   = (float*)(w + 71 * MB);
    float* st   = (float*)(w + 71 * MB + 64 * 1024);
    float* sc   = (float*)(w + 72 * MB);           // head partials (33.5 MB)

    k_prep_all<<<3616, 256, 0, stream>>>(p_qw, p_kw, p_vw, p_ow, p_f1w, p_f2w,
                                         wq16, wk16, wv16, wo16, wf116, wf216, ct, st,
                                         values, dib, gamma, mtyp, in_w, in_b, x);

    for (int l = 0; l < NL; ++l) {
        k_layernorm_w<true><<<2048, 256, 0, stream>>>(x, h16, ln1_s + l * DD, ln1_b + l * DD);
        k_qkv64<<<dim3(128, 6), 256, 0, stream>>>((const short*)h16,
            (const short*)(wq16 + l * 65536), (const short*)(wk16 + l * 65536),
            (const short*)(wv16 + l * 65536),
            p_qb + l * DD, p_kb + l * DD, p_vb + l * DD, ct, st, q16, k16, vt16);
        k_flash<<<dim3(4, BB * HH), 256, 0, stream>>>((const short*)q16, (const short*)k16,
            (const short*)vt16, mask, cx16);
        k_gemm64<2><<<dim3(128, 2), 256, 0, stream>>>((const short*)cx16,
            (const short*)(wo16 + l * 65536), p_ob + l * DD, x, ROWS, DD, DD, x, mask);
        k_layernorm_w<true><<<2048, 256, 0, stream>>>(x, h16, ln2_s + l * DD, ln2_b + l * DD);
        k_gemm_ff1<<<dim3(64, 8), 256, 0, stream>>>((const short*)h16,
            (const short*)(wf116 + l * 262144), p_f1b + l * FFD, f116, ROWS, FFD, DD);
        k_gemm64<3><<<dim3(128, 2), 256, 0, stream>>>((const short*)f116,
            (const short*)(wf216 + l * 262144), p_f2b + l * DD, x, ROWS, DD, FFD, x, nullptr);
    }

    k_head_part<<<HEAD_NCH, 256, 0, stream>>>(x, fn_s, fn_b, head_w, sc);
    k_head_reduce<<<64, 512, 0, stream>>>(sc, head_b, out);
}

// Round 14
// 342.065 us; speedup vs baseline: 1.1346x; 1.0179x over previous
//
#include <hip/hip_runtime.h>
#include <math.h>

#define BB 16
#define SS 512
#define DD 256
#define HH 8
#define HDIM 32
#define FFD 1024
#define NL 2
#define NSOUT 1024
#define SD (SS*DD)      // 131072
#define ROWS (BB*SS)    // 8192

#define HEAD_KC 256
#define HEAD_NCH 512    // SD / HEAD_KC

typedef __attribute__((ext_vector_type(8))) short short8;
typedef __attribute__((ext_vector_type(4))) float f32x4;

__device__ __forceinline__ unsigned short f2bf(float f) {
    union { float f; unsigned u; } c; c.f = f;
    unsigned u = c.u + 0x7fffu + ((c.u >> 16) & 1u);
    return (unsigned short)(u >> 16);
}

// ------- one-shot prep: weight transposes + rope tables + input projection -------
__global__ __launch_bounds__(256) void k_prep_all(
    const float* __restrict__ p_qw, const float* __restrict__ p_kw,
    const float* __restrict__ p_vw, const float* __restrict__ p_ow,
    const float* __restrict__ p_f1w, const float* __restrict__ p_f2w,
    unsigned short* __restrict__ wq, unsigned short* __restrict__ wk,
    unsigned short* __restrict__ wv, unsigned short* __restrict__ wo,
    unsigned short* __restrict__ wf1, unsigned short* __restrict__ wf2,
    float* __restrict__ ct, float* __restrict__ st,
    const float* __restrict__ values, const float* __restrict__ dib,
    const float* __restrict__ gamma, const float* __restrict__ mtyp,
    const float* __restrict__ in_w, const float* __restrict__ in_b,
    float* __restrict__ x) {
    int bid = blockIdx.x;
    int t = threadIdx.x;
    if (bid >= 1568) {   // input projection: 2048 blocks
        int i = (bid - 1568) * 256 + t;   // ROWS*64
        int row = i >> 6, d4 = (i & 63) * 4;
        float v = values[row];
        float f0 = (v >= 0.f) ? 1.f : -1.f;
        float f1 = fabsf(v);
        float f2 = gamma[row];
        float f3 = dib[row];
        float f4 = mtyp[row] * 2.f - 1.f;
        float4 w0 = *(const float4*)&in_w[d4];
        float4 w1 = *(const float4*)&in_w[DD + d4];
        float4 w2 = *(const float4*)&in_w[2 * DD + d4];
        float4 w3 = *(const float4*)&in_w[3 * DD + d4];
        float4 w4 = *(const float4*)&in_w[4 * DD + d4];
        float4 bb = *(const float4*)&in_b[d4];
        float4 o;
        o.x = f0 * w0.x + f1 * w1.x + f2 * w2.x + f3 * w3.x + f4 * w4.x + bb.x;
        o.y = f0 * w0.y + f1 * w1.y + f2 * w2.y + f3 * w3.y + f4 * w4.y + bb.y;
        o.z = f0 * w0.z + f1 * w1.z + f2 * w2.z + f3 * w3.z + f4 * w4.z + bb.z;
        o.w = f0 * w0.w + f1 * w1.w + f2 * w2.w + f3 * w3.w + f4 * w4.w + bb.w;
        *(float4*)&x[(size_t)row * DD + d4] = o;
        return;
    }
    if (bid >= 1536) {   // rope tables
        int i = (bid - 1536) * 256 + t;
        if (i < SS * 16) {
            int s = i >> 4, f = i & 15;
            float invf = powf(10000.f, -(float)f / 16.f);
            float ang = (float)s * invf;
            ct[i] = cosf(ang);
            st[i] = sinf(ang);
        }
        return;
    }
    const float* src; unsigned short* dst;
    int K, N, kx, nx, l;
    if (bid < 512) {
        int grp = bid >> 7, r = bid & 127; l = r >> 6; int tl = r & 63;
        kx = tl >> 3; nx = tl & 7; K = DD; N = DD;
        src = grp == 0 ? p_qw : grp == 1 ? p_kw : grp == 2 ? p_vw : p_ow;
        dst = grp == 0 ? wq : grp == 1 ? wk : grp == 2 ? wv : wo;
    } else if (bid < 1024) {
        int r = bid - 512; l = r >> 8; int tl = r & 255;
        kx = tl >> 5; nx = tl & 31; K = DD; N = FFD; src = p_f1w; dst = wf1;
    } else {
        int r = bid - 1024; l = r >> 8; int tl = r & 255;
        kx = tl >> 3; nx = tl & 7; K = FFD; N = DD; src = p_f2w; dst = wf2;
    }
    __shared__ float tile[32][33];
    size_t zo = (size_t)l * K * N;
    int k0 = kx * 32, n0 = nx * 32;
    int r_ = t >> 3, c4 = (t & 7) * 4;
    float4 a = *(const float4*)&src[zo + (size_t)(k0 + r_) * N + n0 + c4];
    tile[r_][c4 + 0] = a.x; tile[r_][c4 + 1] = a.y; tile[r_][c4 + 2] = a.z; tile[r_][c4 + 3] = a.w;
    __syncthreads();
    unsigned o0 = f2bf(tile[c4 + 0][r_]), o1 = f2bf(tile[c4 + 1][r_]);
    unsigned o2 = f2bf(tile[c4 + 2][r_]), o3 = f2bf(tile[c4 + 3][r_]);
    uint2 ud = { o0 | (o1 << 16), o2 | (o3 << 16) };
    *(uint2*)&dst[zo + (size_t)(n0 + r_) * K + k0 + c4] = ud;
}

// ---------------- wave-per-row layernorm over D=256, no barriers ----------------
template <bool OBF>
__global__ __launch_bounds__(256) void k_layernorm_w(
    const float* __restrict__ in, void* __restrict__ outp,
    const float* __restrict__ sc, const float* __restrict__ bi) {
    int t = threadIdx.x, lane = t & 63, w = t >> 6;
    int row = blockIdx.x * 4 + w;
    float4 v = *(const float4*)&in[(size_t)row * DD + lane * 4];
    float s1 = v.x + v.y + v.z + v.w;
    float s2 = v.x * v.x + v.y * v.y + v.z * v.z + v.w * v.w;
#pragma unroll
    for (int off = 32; off > 0; off >>= 1) {
        s1 += __shfl_xor(s1, off);
        s2 += __shfl_xor(s2, off);
    }
    float mean = s1 * (1.f / DD);
    float var = s2 * (1.f / DD) - mean * mean;
    float rstd = rsqrtf(var + 1e-5f);
    float4 sv = *(const float4*)&sc[lane * 4];
    float4 bv = *(const float4*)&bi[lane * 4];
    float o0 = (v.x - mean) * rstd * sv.x + bv.x;
    float o1 = (v.y - mean) * rstd * sv.y + bv.y;
    float o2 = (v.z - mean) * rstd * sv.z + bv.z;
    float o3 = (v.w - mean) * rstd * sv.w + bv.w;
    if (OBF) {
        ushort4 u = { f2bf(o0), f2bf(o1), f2bf(o2), f2bf(o3) };
        *(ushort4*)&((unsigned short*)outp)[(size_t)row * DD + lane * 4] = u;
    } else {
        float4 o = { o0, o1, o2, o3 };
        *(float4*)&((float*)outp)[(size_t)row * DD + lane * 4] = o;
    }
}

// ---------------- bf16 MFMA GEMM 128x128 (FF1): C = A@Bt^T + bias, exact GELU, bf16 out
__global__ __launch_bounds__(256) void k_gemm_ff1(
    const short* __restrict__ A, const short* __restrict__ Bt,
    const float* __restrict__ bias, unsigned short* __restrict__ Cout,
    int M, int N, int K) {
    __shared__ __align__(16) short As[128 * 32];
    __shared__ __align__(16) short Bs[128 * 32];
    int t = threadIdx.x;
    int lane = t & 63, wid = t >> 6;
    int wr = wid >> 1, wc = wid & 1;
    int m0 = blockIdx.x * 128, n0 = blockIdx.y * 128;
    f32x4 acc[4][4] = {};
    int srow = t >> 2, sslot = t & 3;
    for (int k0 = 0; k0 < K; k0 += 32) {
#pragma unroll
        for (int p = 0; p < 2; ++p) {
            int row = srow + p * 64;
            int sw = sslot ^ ((row >> 1) & 3);
            *(float4*)&As[row * 32 + sw * 8] =
                *(const float4*)&A[(size_t)(m0 + row) * K + k0 + sslot * 8];
            *(float4*)&Bs[row * 32 + sw * 8] =
                *(const float4*)&Bt[(size_t)(n0 + row) * K + k0 + sslot * 8];
        }
        __syncthreads();
        short8 af[4], bfr[4];
#pragma unroll
        for (int mt = 0; mt < 4; ++mt) {
            int row = wr * 64 + mt * 16 + (lane & 15);
            int sl = (lane >> 4) ^ ((row >> 1) & 3);
            af[mt] = *(const short8*)&As[row * 32 + sl * 8];
        }
#pragma unroll
        for (int nt = 0; nt < 4; ++nt) {
            int row = wc * 64 + nt * 16 + (lane & 15);
            int sl = (lane >> 4) ^ ((row >> 1) & 3);
            bfr[nt] = *(const short8*)&Bs[row * 32 + sl * 8];
        }
#pragma unroll
        for (int mt = 0; mt < 4; ++mt)
#pragma unroll
            for (int nt = 0; nt < 4; ++nt)
                acc[mt][nt] = __builtin_amdgcn_mfma_f32_16x16x32_bf16(af[mt], bfr[nt], acc[mt][nt], 0, 0, 0);
        __syncthreads();
    }
#pragma unroll
    for (int mt = 0; mt < 4; ++mt) {
#pragma unroll
        for (int i = 0; i < 4; ++i) {
            int gm = m0 + wr * 64 + mt * 16 + (lane >> 4) * 4 + i;
#pragma unroll
            for (int nt = 0; nt < 4; ++nt) {
                int gn = n0 + wc * 64 + nt * 16 + (lane & 15);
                float v = acc[mt][nt][i] + bias[gn];
                v = 0.5f * v * (1.f + erff(v * 0.70710678118654752f));
                Cout[(size_t)gm * N + gn] = f2bf(v);
            }
        }
    }
}

// ---------------- bf16 MFMA GEMM 64x128, K_STEP=64 (O-proj / FF2), fp32 residual out
template <int EPI>
__global__ __launch_bounds__(256) void k_gemm64(
    const short* __restrict__ A, const short* __restrict__ Bt,
    const float* __restrict__ bias, float* __restrict__ Cout,
    int M, int N, int K, const float* __restrict__ resx, const int* __restrict__ mask) {
    __shared__ __align__(16) short As[64 * 64];    // 8 KB
    __shared__ __align__(16) short Bs[128 * 64];   // 16 KB
    int t = threadIdx.x;
    int lane = t & 63, wid = t >> 6;
    int wr = wid >> 1, wc = wid & 1;          // wave: 32 rows x 64 cols
    int m0 = blockIdx.x * 64, n0 = blockIdx.y * 128;
    int l15 = lane & 15, lh = lane >> 4;
    f32x4 acc[2][4] = {};
    for (int k0 = 0; k0 < K; k0 += 64) {
#pragma unroll
        for (int p = 0; p < 2; ++p) {
            int idx = t + p * 256;
            int row = idx >> 3, sl = idx & 7;
            int sw = sl ^ (row & 7);
            *(float4*)&As[row * 64 + sw * 8] =
                *(const float4*)&A[(size_t)(m0 + row) * K + k0 + sl * 8];
        }
#pragma unroll
        for (int p = 0; p < 4; ++p) {
            int idx = t + p * 256;
            int row = idx >> 3, sl = idx & 7;
            int sw = sl ^ (row & 7);
            *(float4*)&Bs[row * 64 + sw * 8] =
                *(const float4*)&Bt[(size_t)(n0 + row) * K + k0 + sl * 8];
        }
        __syncthreads();
#pragma unroll
        for (int kk = 0; kk < 2; ++kk) {
            short8 af[2], bfr[4];
#pragma unroll
            for (int mt = 0; mt < 2; ++mt) {
                int row = wr * 32 + mt * 16 + l15;
                int sl = (kk * 4 + lh) ^ (row & 7);
                af[mt] = *(const short8*)&As[row * 64 + sl * 8];
            }
#pragma unroll
            for (int nt = 0; nt < 4; ++nt) {
                int row = wc * 64 + nt * 16 + l15;
                int sl = (kk * 4 + lh) ^ (row & 7);
                bfr[nt] = *(const short8*)&Bs[row * 64 + sl * 8];
            }
#pragma unroll
            for (int mt = 0; mt < 2; ++mt)
#pragma unroll
                for (int nt = 0; nt < 4; ++nt)
                    acc[mt][nt] = __builtin_amdgcn_mfma_f32_16x16x32_bf16(af[mt], bfr[nt], acc[mt][nt], 0, 0, 0);
        }
        __syncthreads();
    }
#pragma unroll
    for (int mt = 0; mt < 2; ++mt) {
#pragma unroll
        for (int i = 0; i < 4; ++i) {
            int gm = m0 + wr * 32 + mt * 16 + lh * 4 + i;
            float mk = 1.f;
            if (EPI == 2) mk = (mask[gm] != 0) ? 1.f : 0.f;
#pragma unroll
            for (int nt = 0; nt < 4; ++nt) {
                int gn = n0 + wc * 64 + nt * 16 + l15;
                float v = acc[mt][nt][i] + bias[gn];
                v = resx[(size_t)gm * N + gn] + v * mk;
                Cout[(size_t)gm * N + gn] = v;
            }
        }
    }
}

// ---------------- fused QKV GEMM (64x128 tiles) + bias + RoPE(+scale) / V-transpose --
__global__ __launch_bounds__(256) void k_qkv64(
    const short* __restrict__ A,
    const short* __restrict__ Wq, const short* __restrict__ Wk, const short* __restrict__ Wv,
    const float* __restrict__ bq, const float* __restrict__ bk, const float* __restrict__ bv,
    const float* __restrict__ ct, const float* __restrict__ st,
    unsigned short* __restrict__ q16, unsigned short* __restrict__ k16,
    unsigned short* __restrict__ vt16) {
    __shared__ __align__(16) short As[64 * 32];
    __shared__ __align__(16) short Bs[128 * 32];
    int mat = blockIdx.y >> 1;
    int n0 = (blockIdx.y & 1) * 128;
    const short* Bt = (mat == 0) ? Wq : (mat == 1) ? Wk : Wv;
    const float* bias = (mat == 0) ? bq : (mat == 1) ? bk : bv;
    int t = threadIdx.x;
    int lane = t & 63, wid = t >> 6;
    int wr = wid >> 1, wc = wid & 1;
    int m0 = blockIdx.x * 64;
    int l15 = lane & 15, lh = lane >> 4;
    f32x4 acc[2][4] = {};
    int srow = t >> 2, sslot = t & 3;
    for (int k0 = 0; k0 < DD; k0 += 32) {
        {
            int sw = sslot ^ ((srow >> 1) & 3);
            *(float4*)&As[srow * 32 + sw * 8] =
                *(const float4*)&A[(size_t)(m0 + srow) * DD + k0 + sslot * 8];
        }
#pragma unroll
        for (int p = 0; p < 2; ++p) {
            int row = srow + p * 64;
            int sw = sslot ^ ((row >> 1) & 3);
            *(float4*)&Bs[row * 32 + sw * 8] =
                *(const float4*)&Bt[(size_t)(n0 + row) * DD + k0 + sslot * 8];
        }
        __syncthreads();
        short8 af[2], bfr[4];
#pragma unroll
        for (int mt = 0; mt < 2; ++mt) {
            int row = wr * 32 + mt * 16 + l15;
            int sl = lh ^ ((row >> 1) & 3);
            af[mt] = *(const short8*)&As[row * 32 + sl * 8];
        }
#pragma unroll
        for (int nt = 0; nt < 4; ++nt) {
            int row = wc * 64 + nt * 16 + l15;
            int sl = lh ^ ((row >> 1) & 3);
            bfr[nt] = *(const short8*)&Bs[row * 32 + sl * 8];
        }
#pragma unroll
        for (int mt = 0; mt < 2; ++mt)
#pragma unroll
            for (int nt = 0; nt < 4; ++nt)
                acc[mt][nt] = __builtin_amdgcn_mfma_f32_16x16x32_bf16(af[mt], bfr[nt], acc[mt][nt], 0, 0, 0);
        __syncthreads();
    }
    float bs[4];
#pragma unroll
    for (int nt = 0; nt < 4; ++nt) bs[nt] = bias[n0 + wc * 64 + nt * 16 + l15];
    if (mat < 2) {
        unsigned short* dst = (mat == 0) ? q16 : k16;
        const float qscale = (mat == 0) ? 0.17677669529663687f : 1.f;  // fold 1/sqrt(32) into Q
#pragma unroll
        for (int mt = 0; mt < 2; ++mt) {
#pragma unroll
            for (int i = 0; i < 4; ++i) {
                int gm = m0 + wr * 32 + mt * 16 + lh * 4 + i;
                int s = gm & (SS - 1);
                float c = ct[s * 16 + l15], sn = st[s * 16 + l15];
                float val[4];
#pragma unroll
                for (int nt = 0; nt < 4; ++nt) val[nt] = (acc[mt][nt][i] + bs[nt]) * qscale;
#pragma unroll
                for (int nt = 0; nt < 4; ++nt) {
                    float partner = val[nt ^ 1];
                    float o = ((nt & 1) == 0) ? (val[nt] * c - partner * sn)
                                              : (val[nt] * c + partner * sn);
                    dst[(size_t)gm * DD + n0 + wc * 64 + nt * 16 + l15] = f2bf(o);
                }
            }
        }
    } else {
#pragma unroll
        for (int mt = 0; mt < 2; ++mt) {
            int gmb = m0 + wr * 32 + mt * 16 + lh * 4;
            int b = gmb >> 9, sb = gmb & (SS - 1);
#pragma unroll
            for (int nt = 0; nt < 4; ++nt) {
                int gn = n0 + wc * 64 + nt * 16 + l15;
                int h = gn >> 5, d = gn & 31;
                ushort4 u;
#pragma unroll
                for (int i = 0; i < 4; ++i)
                    (&u.x)[i] = f2bf(acc[mt][nt][i] + bs[nt]);
                *(ushort4*)&vt16[((size_t)((b * HH + h) * HDIM + d)) * SS + sb] = u;
            }
        }
    }
}

// ---------------- fused flash attention (Q pre-scaled) ----------------
__global__ __launch_bounds__(256) void k_flash(
    const short* __restrict__ qb, const short* __restrict__ kb,
    const short* __restrict__ vt, const int* __restrict__ mask,
    unsigned short* __restrict__ ctxb) {
    __shared__ float bias_lds[SS];
    __shared__ __align__(16) short p_lds[4][32 * 72];
    __shared__ __align__(16) float r_lds[4][32];
    int t = threadIdx.x, lane = t & 63, wq = t >> 6;
    int bh = blockIdx.y;
    int b = bh >> 3, h = bh & 7;
    int q0 = blockIdx.x * 128 + wq * 32;
    bias_lds[t]       = (mask[b * SS + t]       != 0) ? 0.f : -3.0e38f;
    bias_lds[t + 256] = (mask[b * SS + t + 256] != 0) ? 0.f : -3.0e38f;
    __syncthreads();
    int l15 = lane & 15, lh = lane >> 4;
    short8 qfr[2];
    qfr[0] = *(const short8*)&qb[((size_t)(b * SS) + q0 + l15) * DD + h * HDIM + lh * 8];
    qfr[1] = *(const short8*)&qb[((size_t)(b * SS) + q0 + 16 + l15) * DD + h * HDIM + lh * 8];
    float m[2] = {-3.0e38f, -3.0e38f};
    float lsum[2] = {0.f, 0.f};
    f32x4 oacc[2][2] = {};   // [mf = q-frag][df = d-frag]
    for (int k0 = 0; k0 < SS; k0 += 64) {
        f32x4 sT[4][2];
#pragma unroll
        for (int kt = 0; kt < 4; ++kt) {
            short8 kf = *(const short8*)&kb[((size_t)(b * SS) + k0 + kt * 16 + l15) * DD + h * HDIM + lh * 8];
#pragma unroll
            for (int qf = 0; qf < 2; ++qf) {
                f32x4 z = {0.f, 0.f, 0.f, 0.f};
                sT[kt][qf] = __builtin_amdgcn_mfma_f32_16x16x32_bf16(kf, qfr[qf], z, 0, 0, 0);
            }
        }
        float p[2][16];
        float r[2];
#pragma unroll
        for (int qf = 0; qf < 2; ++qf) {
            float pmax = -3.0e38f;
#pragma unroll
            for (int kt = 0; kt < 4; ++kt)
#pragma unroll
                for (int i = 0; i < 4; ++i) {
                    float s = sT[kt][qf][i] + bias_lds[k0 + kt * 16 + lh * 4 + i];
                    p[qf][kt * 4 + i] = s;
                    pmax = fmaxf(pmax, s);
                }
            pmax = fmaxf(pmax, __shfl_xor(pmax, 16));
            pmax = fmaxf(pmax, __shfl_xor(pmax, 32));
            float mn = fmaxf(m[qf], pmax);
            r[qf] = __expf(m[qf] - mn);
            m[qf] = mn;
            float cs = 0.f;
#pragma unroll
            for (int j = 0; j < 16; ++j) {
                float e = __expf(p[qf][j] - mn);
                p[qf][j] = e;
                cs += e;
            }
            cs += __shfl_xor(cs, 16);
            cs += __shfl_xor(cs, 32);
            lsum[qf] = lsum[qf] * r[qf] + cs;
        }
#pragma unroll
        for (int qf = 0; qf < 2; ++qf) {
            int qq = qf * 16 + l15;
#pragma unroll
            for (int kt = 0; kt < 4; ++kt) {
                unsigned u0 = (unsigned)f2bf(p[qf][kt * 4 + 0]) | ((unsigned)f2bf(p[qf][kt * 4 + 1]) << 16);
                unsigned u1 = (unsigned)f2bf(p[qf][kt * 4 + 2]) | ((unsigned)f2bf(p[qf][kt * 4 + 3]) << 16);
                uint2 u = { u0, u1 };
                *(uint2*)&p_lds[wq][qq * 72 + kt * 16 + lh * 4] = u;
            }
        }
        if (lane < 16) { r_lds[wq][l15] = r[0]; r_lds[wq][16 + l15] = r[1]; }
        __syncthreads();
#pragma unroll
        for (int mf = 0; mf < 2; ++mf) {
            float4 rv = *(const float4*)&r_lds[wq][mf * 16 + lh * 4];
#pragma unroll
            for (int df = 0; df < 2; ++df) {
                oacc[mf][df][0] *= rv.x; oacc[mf][df][1] *= rv.y;
                oacc[mf][df][2] *= rv.z; oacc[mf][df][3] *= rv.w;
            }
        }
#pragma unroll
        for (int ks = 0; ks < 2; ++ks) {
            short8 pa0 = *(const short8*)&p_lds[wq][(l15) * 72 + ks * 32 + lh * 8];
            short8 pa1 = *(const short8*)&p_lds[wq][(16 + l15) * 72 + ks * 32 + lh * 8];
#pragma unroll
            for (int df = 0; df < 2; ++df) {
                short8 vf = *(const short8*)&vt[((size_t)bh * HDIM + df * 16 + l15) * SS + k0 + ks * 32 + lh * 8];
                oacc[0][df] = __builtin_amdgcn_mfma_f32_16x16x32_bf16(pa0, vf, oacc[0][df], 0, 0, 0);
                oacc[1][df] = __builtin_amdgcn_mfma_f32_16x16x32_bf16(pa1, vf, oacc[1][df], 0, 0, 0);
            }
        }
        __syncthreads();
    }
    if (lane < 16) { r_lds[wq][l15] = 1.f / lsum[0]; r_lds[wq][16 + l15] = 1.f / lsum[1]; }
    __syncthreads();
#pragma unroll
    for (int mf = 0; mf < 2; ++mf) {
        float4 lv = *(const float4*)&r_lds[wq][mf * 16 + lh * 4];
        const float li[4] = { lv.x, lv.y, lv.z, lv.w };
#pragma unroll
        for (int df = 0; df < 2; ++df)
#pragma unroll
            for (int i = 0; i < 4; ++i) {
                int gq = q0 + mf * 16 + lh * 4 + i;
                int gd = df * 16 + l15;
                ctxb[((size_t)(b * SS) + gq) * DD + h * HDIM + gd] = f2bf(oacc[mf][df][i] * li[i]);
            }
    }
}

// ---------------- head: fused final-LN + fp32 partial GEMV (nontemporal W) ----------
__global__ __launch_bounds__(256) void k_head_part(
    const float* __restrict__ x, const float* __restrict__ fns, const float* __restrict__ fnb,
    const float* __restrict__ W, float* __restrict__ part) {
    __shared__ float xs[16 * HEAD_KC];
    int c = blockIdx.x;
    int t = threadIdx.x, lane = t & 63, w = t >> 6;
    float4 sv = *(const float4*)&fns[lane * 4];
    float4 bv = *(const float4*)&fnb[lane * 4];
#pragma unroll
    for (int rr = 0; rr < 4; ++rr) {
        int b = w * 4 + rr;
        float4 v = *(const float4*)&x[(size_t)b * SD + c * HEAD_KC + lane * 4];
        float s1 = v.x + v.y + v.z + v.w;
        float s2 = v.x * v.x + v.y * v.y + v.z * v.z + v.w * v.w;
#pragma unroll
        for (int off = 32; off > 0; off >>= 1) {
            s1 += __shfl_xor(s1, off);
            s2 += __shfl_xor(s2, off);
        }
        float mean = s1 * (1.f / DD);
        float var = s2 * (1.f / DD) - mean * mean;
        float rstd = rsqrtf(var + 1e-5f);
        float4 o;
        o.x = (v.x - mean) * rstd * sv.x + bv.x;
        o.y = (v.y - mean) * rstd * sv.y + bv.y;
        o.z = (v.z - mean) * rstd * sv.z + bv.z;
        o.w = (v.w - mean) * rstd * sv.w + bv.w;
        *(float4*)&xs[b * HEAD_KC + lane * 4] = o;
    }
    __syncthreads();
    int k0 = c * HEAD_KC;
    int n4 = t * 4;
    float acc[16][4] = {};
#pragma unroll 8
    for (int k = 0; k < HEAD_KC; ++k) {
        f32x4 wv = __builtin_nontemporal_load((const f32x4*)&W[(size_t)(k0 + k) * NSOUT + n4]);
#pragma unroll
        for (int b = 0; b < 16; ++b) {
            float xv = xs[b * HEAD_KC + k];
            acc[b][0] += xv * wv[0]; acc[b][1] += xv * wv[1];
            acc[b][2] += xv * wv[2]; acc[b][3] += xv * wv[3];
        }
    }
#pragma unroll
    for (int b = 0; b < 16; ++b) {
        float4 o = {acc[b][0], acc[b][1], acc[b][2], acc[b][3]};
        *(float4*)&part[((size_t)c * 16 + b) * NSOUT + n4] = o;
    }
}

// ---------------- head reduce: 64 blocks x 512 threads, 8 c-groups ----------------
__global__ __launch_bounds__(512) void k_head_reduce(
    const float* __restrict__ part, const float* __restrict__ hb,
    float* __restrict__ out) {
    __shared__ float red[8][260];
    int t = threadIdx.x;
    int col = t & 63;            // float4 column within the block's 256-output slice
    int grp = t >> 6;            // 0..7
    int base = blockIdx.x * 256; // 64 blocks x 256 outputs = 16384
    f32x4 s = {0.f, 0.f, 0.f, 0.f};
#pragma unroll 8
    for (int c = grp; c < HEAD_NCH; c += 8) {
        f32x4 p = *(const f32x4*)&part[(size_t)c * (16 * NSOUT) + base + col * 4];
        s[0] += p[0]; s[1] += p[1]; s[2] += p[2]; s[3] += p[3];
    }
    red[grp][col * 4 + 0] = s[0];
    red[grp][col * 4 + 1] = s[1];
    red[grp][col * 4 + 2] = s[2];
    red[grp][col * 4 + 3] = s[3];
    __syncthreads();
    if (t < 256) {
        float acc = 0.f;
#pragma unroll
        for (int g = 0; g < 8; ++g) acc += red[g][t];
        out[base + t] = acc + hb[(base + t) & (NSOUT - 1)];
    }
}

extern "C" void kernel_launch(void* const* d_in, const int* in_sizes, int n_in,
                              void* d_out, int out_size, void* d_ws, size_t ws_size,
                              hipStream_t stream) {
    const float* values = (const float*)d_in[0];
    const float* dib    = (const float*)d_in[1];
    const float* gamma  = (const float*)d_in[2];
    const float* mtyp   = (const float*)d_in[3];
    const int*   mask   = (const int*)d_in[4];
    const float* in_w   = (const float*)d_in[5];
    const float* in_b   = (const float*)d_in[6];
    const float* ln1_s  = (const float*)d_in[7];
    const float* ln1_b  = (const float*)d_in[8];
    const float* p_qw   = (const float*)d_in[9];
    const float* p_qb   = (const float*)d_in[10];
    const float* p_kw   = (const float*)d_in[11];
    const float* p_kb   = (const float*)d_in[12];
    const float* p_vw   = (const float*)d_in[13];
    const float* p_vb   = (const float*)d_in[14];
    const float* p_ow   = (const float*)d_in[15];
    const float* p_ob   = (const float*)d_in[16];
    const float* ln2_s  = (const float*)d_in[17];
    const float* ln2_b  = (const float*)d_in[18];
    const float* p_f1w  = (const float*)d_in[19];
    const float* p_f1b  = (const float*)d_in[20];
    const float* p_f2w  = (const float*)d_in[21];
    const float* p_f2b  = (const float*)d_in[22];
    const float* fn_s   = (const float*)d_in[23];
    const float* fn_b   = (const float*)d_in[24];
    const float* head_w = (const float*)d_in[25];
    const float* head_b = (const float*)d_in[26];
    float* out = (float*)d_out;

    const size_t MB = 1u << 20;
    char* w = (char*)d_ws;
    float* x    = (float*)(w + 0 * MB);            // 8 MB fp32 residual stream
    unsigned short* h16  = (unsigned short*)(w + 32 * MB);  // 4 MB each
    unsigned short* q16  = (unsigned short*)(w + 36 * MB);
    unsigned short* k16  = (unsigned short*)(w + 40 * MB);
    unsigned short* vt16 = (unsigned short*)(w + 44 * MB);
    unsigned short* cx16 = (unsigned short*)(w + 48 * MB);
    unsigned short* f116 = (unsigned short*)(w + 52 * MB);  // 16 MB
    unsigned short* wq16 = (unsigned short*)(w + 68 * MB);  // 256 KB each (2 layers)
    unsigned short* wk16 = (unsigned short*)(w + 68 * MB + 256 * 1024);
    unsigned short* wv16 = (unsigned short*)(w + 68 * MB + 512 * 1024);
    unsigned short* wo16 = (unsigned short*)(w + 68 * MB + 768 * 1024);
    unsigned short* wf116 = (unsigned short*)(w + 69 * MB); // 1 MB
    unsigned short* wf216 = (unsigned short*)(w + 70 * MB); // 1 MB
    float* ct   = (float*)(w + 71 * MB);
    float* st   = (float*)(w + 71 * MB + 64 * 1024);
    float* sc   = (float*)(w + 72 * MB);           // head partials (33.5 MB)

    k_prep_all<<<3616, 256, 0, stream>>>(p_qw, p_kw, p_vw, p_ow, p_f1w, p_f2w,
                                         wq16, wk16, wv16, wo16, wf116, wf216, ct, st,
                                         values, dib, gamma, mtyp, in_w, in_b, x);

    for (int l = 0; l < NL; ++l) {
        k_layernorm_w<true><<<2048, 256, 0, stream>>>(x, h16, ln1_s + l * DD, ln1_b + l * DD);
        k_qkv64<<<dim3(128, 6), 256, 0, stream>>>((const short*)h16,
            (const short*)(wq16 + l * 65536), (const short*)(wk16 + l * 65536),
            (const short*)(wv16 + l * 65536),
            p_qb + l * DD, p_kb + l * DD, p_vb + l * DD, ct, st, q16, k16, vt16);
        k_flash<<<dim3(4, BB * HH), 256, 0, stream>>>((const short*)q16, (const short*)k16,
            (const short*)vt16, mask, cx16);
        k_gemm64<2><<<dim3(128, 2), 256, 0, stream>>>((const short*)cx16,
            (const short*)(wo16 + l * 65536), p_ob + l * DD, x, ROWS, DD, DD, x, mask);
        k_layernorm_w<true><<<2048, 256, 0, stream>>>(x, h16, ln2_s + l * DD, ln2_b + l * DD);
        k_gemm_ff1<<<dim3(64, 8), 256, 0, stream>>>((const short*)h16,
            (const short*)(wf116 + l * 262144), p_f1b + l * FFD, f116, ROWS, FFD, DD);
        k_gemm64<3><<<dim3(128, 2), 256, 0, stream>>>((const short*)f116,
            (const short*)(wf216 + l * 262144), p_f2b + l * DD, x, ROWS, DD, FFD, x, nullptr);
    }

    k_head_part<<<HEAD_NCH, 256, 0, stream>>>(x, fn_s, fn_b, head_w, sc);
    k_head_reduce<<<64, 512, 0, stream>>>(sc, head_b, out);
}